// Round 5
// baseline (577.298 us; speedup 1.0000x reference)
//
#include <hip/hip_runtime.h>
#include <math.h>

#define NN   100000
#define EE   1600000
#define FIN  256
#define NCLS 16
#define NEG  0.2f

#define NEDGE (EE + NN)   // with self-loops
#define NBLK  ((NN + 255) / 256)   // 391 scan blocks

// ---- workspace layout (4-byte element offsets) ----
#define OFF_DEG   0                    // [NN] int, zeroed
#define OFF_CNT   (NN)                 // [NN] int, zeroed
#define NZERO_I   (2*NN)
#define OFF_ROW   (2*NN)               // [NN+1] int
#define OFF_TMP   (3*NN + 4)           // [NN] int
#define OFF_BSUM  (4*NN + 8)           // [512] int
#define OFF_ADJ   (4*NN + 520)         // [NEDGE] int (src per slot, CSR by dst)
#define OFF_H1B   (OFF_ADJ + NEDGE)    // [NN*64] bf16 (pre-attention values)
#define OFF_H1E   (OFF_H1B + NN*32)    // [NN*64] bf16 (post-ELU layer-1 output)
#define OFF_AL1S  (OFF_H1E + NN*32)    // [NN*8]
#define OFF_AL1D  (OFF_AL1S + NN*8)    // [NN*8]
#define OFF_AL2S  (OFF_AL1D + NN*8)    // [NN]
#define OFF_AL2D  (OFF_AL2S + NN)      // [NN]
#define OFF_VA    (OFF_AL2D + NN)      // [64]  W2 @ a2s
#define OFF_VD    (OFF_VA + 64)        // [64]  W2 @ a2d

__device__ __forceinline__ float lrelu(float x) { return x >= 0.f ? x : NEG * x; }
__device__ __forceinline__ unsigned short f2bf(float x) {
    unsigned u = __float_as_uint(x);
    return (unsigned short)((u + 0x7FFF + ((u >> 16) & 1)) >> 16);   // RNE
}
__device__ __forceinline__ float bf2f(unsigned short b) {
    return __uint_as_float(((unsigned)b) << 16);
}

// ---------- CSR build ----------
__global__ __launch_bounds__(256) void k_hist(
    const int* __restrict__ edst, int* __restrict__ deg)
{
    int ei = blockIdx.x * 256 + threadIdx.x;
    if (ei >= NEDGE) return;
    int d = (ei < EE) ? edst[ei] : ei - EE;
    atomicAdd(&deg[d], 1);
}

__global__ __launch_bounds__(256) void k_scan1(
    const int* __restrict__ deg, int* __restrict__ tmp, int* __restrict__ bsum)
{
    __shared__ int s[256];
    int t = threadIdx.x;
    int i = blockIdx.x * 256 + t;
    int v = (i < NN) ? deg[i] : 0;
    s[t] = v;
    __syncthreads();
    for (int off = 1; off < 256; off <<= 1) {
        int u = (t >= off) ? s[t - off] : 0;
        __syncthreads();
        s[t] += u;
        __syncthreads();
    }
    if (i < NN) tmp[i] = s[t] - v;
    if (t == 255) bsum[blockIdx.x] = s[255];
}

__global__ __launch_bounds__(512) void k_scan2(int* __restrict__ bsum)
{
    __shared__ int s[512];
    int t = threadIdx.x;
    int v = (t < NBLK) ? bsum[t] : 0;
    s[t] = v;
    __syncthreads();
    for (int off = 1; off < 512; off <<= 1) {
        int u = (t >= off) ? s[t - off] : 0;
        __syncthreads();
        s[t] += u;
        __syncthreads();
    }
    bsum[t] = s[t] - v;
}

__global__ __launch_bounds__(256) void k_scan3(
    const int* __restrict__ tmp, const int* __restrict__ bsum,
    int* __restrict__ row)
{
    int i = blockIdx.x * 256 + threadIdx.x;
    if (i < NN) row[i] = tmp[i] + bsum[blockIdx.x];
    if (i == 0) row[NN] = NEDGE;
}

__global__ __launch_bounds__(256) void k_fill(
    const int* __restrict__ esrc, const int* __restrict__ edst,
    const int* __restrict__ row, int* __restrict__ cnt, int* __restrict__ adj)
{
    int ei = blockIdx.x * 256 + threadIdx.x;
    if (ei >= NEDGE) return;
    int s, d;
    if (ei < EE) { s = esrc[ei]; d = edst[ei]; } else { s = d = ei - EE; }
    int pos = row[d] + atomicAdd(&cnt[d], 1);
    adj[pos] = s;
}

// ---------- tiny prep: va = W2 @ a2s, vd = W2 @ a2d ----------
__global__ __launch_bounds__(64) void k_prep(
    const float* __restrict__ W2, const float* __restrict__ a2s,
    const float* __restrict__ a2d, float* __restrict__ va, float* __restrict__ vd)
{
    int c = threadIdx.x;   // 0..63
    float s = 0.f, d = 0.f;
    #pragma unroll
    for (int k = 0; k < 16; ++k) {
        float w = W2[c * 16 + k];
        s += w * a2s[k];
        d += w * a2d[k];
    }
    va[c] = s; vd[c] = d;
}

// ---------- layer 1 GEMM: 64x64 tile, 4x4 register tile; bf16 value output ----------
__global__ __launch_bounds__(256) void k_gemm1(
    const float* __restrict__ x, const float* __restrict__ W1,
    const float* __restrict__ a1s, const float* __restrict__ a1d,
    unsigned short* __restrict__ h1b, float* __restrict__ al1s, float* __restrict__ al1d)
{
    __shared__ float sxT[32][68];
    __shared__ float sW[32][64];
    const int t = threadIdx.x;
    const int n0 = blockIdx.x * 64;
    const int tr = t >> 4, tc = t & 15;

    float acc[4][4] = {};

    for (int kc = 0; kc < 256; kc += 32) {
        __syncthreads();
        #pragma unroll
        for (int it = 0; it < 2; ++it) {
            int i = t + it * 256;
            int r = i >> 3, fj = i & 7;
            int n = n0 + r;
            float4 v = (n < NN) ? *(const float4*)(x + (size_t)n * FIN + kc + fj * 4)
                                : make_float4(0.f, 0.f, 0.f, 0.f);
            sxT[fj * 4 + 0][r] = v.x;
            sxT[fj * 4 + 1][r] = v.y;
            sxT[fj * 4 + 2][r] = v.z;
            sxT[fj * 4 + 3][r] = v.w;
        }
        #pragma unroll
        for (int it = 0; it < 2; ++it) {
            int i = t + it * 256;
            int r = i >> 4, fj = i & 15;
            *(float4*)&sW[r][fj * 4] = *(const float4*)(W1 + (size_t)(kc + r) * 64 + fj * 4);
        }
        __syncthreads();
        #pragma unroll
        for (int k = 0; k < 32; ++k) {
            float4 a = *(const float4*)&sxT[k][tr * 4];
            float4 b = *(const float4*)&sW[k][tc * 4];
            acc[0][0] += a.x * b.x; acc[0][1] += a.x * b.y; acc[0][2] += a.x * b.z; acc[0][3] += a.x * b.w;
            acc[1][0] += a.y * b.x; acc[1][1] += a.y * b.y; acc[1][2] += a.y * b.z; acc[1][3] += a.y * b.w;
            acc[2][0] += a.z * b.x; acc[2][1] += a.z * b.y; acc[2][2] += a.z * b.z; acc[2][3] += a.z * b.w;
            acc[3][0] += a.w * b.x; acc[3][1] += a.w * b.y; acc[3][2] += a.w * b.z; acc[3][3] += a.w * b.w;
        }
    }

    #pragma unroll
    for (int j = 0; j < 4; ++j) {
        int n = n0 + tr * 4 + j;
        if (n < NN) {
            ushort4 v = make_ushort4(f2bf(acc[j][0]), f2bf(acc[j][1]), f2bf(acc[j][2]), f2bf(acc[j][3]));
            *(ushort4*)(h1b + (size_t)n * 64 + tc * 4) = v;
        }
    }

    float sa[4], da[4];
    #pragma unroll
    for (int u = 0; u < 4; ++u) { sa[u] = a1s[tc * 4 + u]; da[u] = a1d[tc * 4 + u]; }
    #pragma unroll
    for (int j = 0; j < 4; ++j) {
        float vs = acc[j][0] * sa[0] + acc[j][1] * sa[1] + acc[j][2] * sa[2] + acc[j][3] * sa[3];
        float vd = acc[j][0] * da[0] + acc[j][1] * da[1] + acc[j][2] * da[2] + acc[j][3] * da[3];
        vs += __shfl_xor(vs, 1, 64);
        vd += __shfl_xor(vd, 1, 64);
        int n = n0 + tr * 4 + j;
        if (!(tc & 1) && n < NN) {
            al1s[n * 8 + (tc >> 1)] = vs;
            al1d[n * 8 + (tc >> 1)] = vd;
        }
    }
}

// ---------- layer 1 aggregation: online softmax, bf16 gather, fused ELU + layer-2 logits ----------
__global__ __launch_bounds__(256) void k_agg1(
    const int* __restrict__ row, const int* __restrict__ adj,
    const float* __restrict__ al1s, const float* __restrict__ al1d,
    const unsigned short* __restrict__ h1b, const float* __restrict__ b1,
    const float* __restrict__ va, const float* __restrict__ vdv,
    unsigned short* __restrict__ h1e, float* __restrict__ al2s, float* __restrict__ al2d)
{
    const int wv = threadIdx.x >> 6, lane = threadIdx.x & 63;
    const int n = blockIdx.x * 4 + wv;
    const int h = lane >> 3;
    const float ald = al1d[n * 8 + h];
    const int r0 = row[n], r1 = row[n + 1];

    float m = -1e30f, dsum = 0.f, acc = 0.f;
    int i = r0;
    for (; i + 3 < r1; i += 4) {
        int s0 = adj[i], s1 = adj[i + 1], s2 = adj[i + 2], s3 = adj[i + 3];
        float e0 = lrelu(al1s[s0 * 8 + h] + ald);
        float e1 = lrelu(al1s[s1 * 8 + h] + ald);
        float e2 = lrelu(al1s[s2 * 8 + h] + ald);
        float e3 = lrelu(al1s[s3 * 8 + h] + ald);
        unsigned short u0 = h1b[(size_t)s0 * 64 + lane];
        unsigned short u1 = h1b[(size_t)s1 * 64 + lane];
        unsigned short u2 = h1b[(size_t)s2 * 64 + lane];
        unsigned short u3 = h1b[(size_t)s3 * 64 + lane];
        float nm = fmaxf(fmaxf(fmaxf(e0, e1), fmaxf(e2, e3)), m);
        float sc = __expf(m - nm);
        float w0 = __expf(e0 - nm), w1 = __expf(e1 - nm);
        float w2 = __expf(e2 - nm), w3 = __expf(e3 - nm);
        dsum = dsum * sc + (w0 + w1) + (w2 + w3);
        acc  = acc  * sc + (w0 * bf2f(u0) + w1 * bf2f(u1)) + (w2 * bf2f(u2) + w3 * bf2f(u3));
        m = nm;
    }
    for (; i < r1; ++i) {
        int s0 = adj[i];
        float e0 = lrelu(al1s[s0 * 8 + h] + ald);
        unsigned short u0 = h1b[(size_t)s0 * 64 + lane];
        float nm = fmaxf(m, e0);
        float sc = __expf(m - nm), w0 = __expf(e0 - nm);
        dsum = dsum * sc + w0;
        acc  = acc  * sc + w0 * bf2f(u0);
        m = nm;
    }
    float v = acc / dsum + b1[lane];
    v = v > 0.f ? v : __expf(v) - 1.f;       // ELU fused
    h1e[(size_t)n * 64 + lane] = f2bf(v);

    // fused layer-2 attention logits: al2s[n] = v . (W2@a2s), al2d likewise
    float vs = v * va[lane];
    float vd = v * vdv[lane];
    #pragma unroll
    for (int off = 1; off < 64; off <<= 1) {
        vs += __shfl_xor(vs, off, 64);
        vd += __shfl_xor(vd, off, 64);
    }
    if (lane == 0) { al2s[n] = vs; al2d[n] = vd; }
}

// ---------- layer 2: aggregate h1 directly, then W2 matvec + b2 + log_softmax ----------
__global__ __launch_bounds__(256) void k_agg2(
    const int* __restrict__ row, const int* __restrict__ adj,
    const float* __restrict__ al2s, const float* __restrict__ al2d,
    const unsigned short* __restrict__ h1e, const float* __restrict__ W2,
    const float* __restrict__ b2, float* __restrict__ out)
{
    __shared__ float sW[64 * 16];
    __shared__ float sAgg[4][64];
    const int t = threadIdx.x;
    for (int i = t; i < 64 * 16; i += 256) sW[i] = W2[i];
    __syncthreads();

    const int wv = t >> 6, lane = t & 63;
    const int n = blockIdx.x * 4 + wv;
    const float ald = al2d[n];
    const int r0 = row[n], r1 = row[n + 1];

    float m = -1e30f, dsum = 0.f, acc = 0.f;
    int i = r0;
    for (; i + 1 < r1; i += 2) {
        int s0 = adj[i], s1 = adj[i + 1];
        float e0 = lrelu(al2s[s0] + ald);
        float e1 = lrelu(al2s[s1] + ald);
        unsigned short u0 = h1e[(size_t)s0 * 64 + lane];
        unsigned short u1 = h1e[(size_t)s1 * 64 + lane];
        float nm = fmaxf(m, fmaxf(e0, e1));
        float sc = __expf(m - nm);
        float w0 = __expf(e0 - nm), w1 = __expf(e1 - nm);
        dsum = dsum * sc + w0 + w1;
        acc  = acc  * sc + w0 * bf2f(u0) + w1 * bf2f(u1);
        m = nm;
    }
    if (i < r1) {
        int s0 = adj[i];
        float e0 = lrelu(al2s[s0] + ald);
        unsigned short u0 = h1e[(size_t)s0 * 64 + lane];
        float nm = fmaxf(m, e0);
        float sc = __expf(m - nm), w0 = __expf(e0 - nm);
        dsum = dsum * sc + w0;
        acc  = acc  * sc + w0 * bf2f(u0);
        m = nm;
    }
    sAgg[wv][lane] = acc / dsum;    // same-wave LDS write->read, no barrier needed

    // W2 matvec: lane = (q,k), q = channel quarter, k = class
    const int k = lane & 15, q = lane >> 4;
    float p = 0.f;
    #pragma unroll
    for (int cc = 0; cc < 16; ++cc) {
        int c = q * 16 + cc;
        p += sAgg[wv][c] * sW[c * 16 + k];
    }
    p += __shfl_xor(p, 16, 64);
    p += __shfl_xor(p, 32, 64);
    float vk = p + b2[k];

    // log_softmax over the 16 classes (within 16-lane group)
    float mx = vk;
    #pragma unroll
    for (int off = 1; off < 16; off <<= 1) mx = fmaxf(mx, __shfl_xor(mx, off, 64));
    float se = __expf(vk - mx);
    #pragma unroll
    for (int off = 1; off < 16; off <<= 1) se += __shfl_xor(se, off, 64);
    float ls = mx + __logf(se);
    if (q == 0) out[(size_t)n * 16 + k] = vk - ls;
}

extern "C" void kernel_launch(void* const* d_in, const int* in_sizes, int n_in,
                              void* d_out, int out_size, void* d_ws, size_t ws_size,
                              hipStream_t stream)
{
    const float* x    = (const float*)d_in[0];
    const int*   eidx = (const int*)d_in[1];
    const float* W1   = (const float*)d_in[2];
    const float* a1s  = (const float*)d_in[3];
    const float* a1d  = (const float*)d_in[4];
    const float* b1   = (const float*)d_in[5];
    const float* W2   = (const float*)d_in[6];
    const float* a2s  = (const float*)d_in[7];
    const float* a2d  = (const float*)d_in[8];
    const float* b2   = (const float*)d_in[9];
    float* out = (float*)d_out;
    float* ws  = (float*)d_ws;

    const int* esrc = eidx;
    const int* edst = eidx + EE;

    int* deg  = (int*)(ws + OFF_DEG);
    int* cnt  = (int*)(ws + OFF_CNT);
    int* row  = (int*)(ws + OFF_ROW);
    int* tmp  = (int*)(ws + OFF_TMP);
    int* bsum = (int*)(ws + OFF_BSUM);
    int* adj  = (int*)(ws + OFF_ADJ);
    unsigned short* h1b = (unsigned short*)(ws + OFF_H1B);
    unsigned short* h1e = (unsigned short*)(ws + OFF_H1E);
    float* al1s  = ws + OFF_AL1S;
    float* al1d  = ws + OFF_AL1D;
    float* al2s  = ws + OFF_AL2S;
    float* al2d  = ws + OFF_AL2D;
    float* va    = ws + OFF_VA;
    float* vd    = ws + OFF_VD;

    hipMemsetAsync(ws, 0, (size_t)NZERO_I * sizeof(int), stream);

    const int gE = (NEDGE + 255) / 256;
    k_hist <<<gE,   256, 0, stream>>>(edst, deg);
    k_scan1<<<NBLK, 256, 0, stream>>>(deg, tmp, bsum);
    k_scan2<<<1,    512, 0, stream>>>(bsum);
    k_scan3<<<NBLK, 256, 0, stream>>>(tmp, bsum, row);
    k_fill <<<gE,   256, 0, stream>>>(esrc, edst, row, cnt, adj);
    k_prep <<<1,     64, 0, stream>>>(W2, a2s, a2d, va, vd);

    k_gemm1<<<(NN + 63) / 64, 256, 0, stream>>>(x, W1, a1s, a1d, h1b, al1s, al1d);
    k_agg1 <<<NN / 4, 256, 0, stream>>>(row, adj, al1s, al1d, h1b, b1, va, vd, h1e, al2s, al2d);
    k_agg2 <<<NN / 4, 256, 0, stream>>>(row, adj, al2s, al2d, h1e, W2, b2, out);
}

// Round 6
// 508.566 us; speedup vs baseline: 1.1351x; 1.1351x over previous
//
#include <hip/hip_runtime.h>
#include <math.h>

#define NN   100000
#define EE   1600000
#define FIN  256
#define NCLS 16
#define NEG  0.2f

#define NEDGE (EE + NN)   // with self-loops
#define NBLK  ((NN + 255) / 256)   // 391 scan blocks

// ---- workspace layout (4-byte element offsets) ----
#define OFF_DEG   0                    // [NN] int, zeroed
#define OFF_CNT   (NN)                 // [NN] int, zeroed
#define NZERO_I   (2*NN)
#define OFF_ROW   (2*NN)               // [NN+1] int
#define OFF_TMP   (3*NN + 4)           // [NN] int
#define OFF_BSUM  (4*NN + 8)           // [512] int
#define OFF_ADJ   (4*NN + 520)         // [NEDGE] int (src per slot, CSR by dst)
#define OFF_H1B   (OFF_ADJ + NEDGE)    // [NN*64] bf16 (pre-attention values)
#define OFF_H1E   (OFF_H1B + NN*32)    // [NN*64] bf16 (post-ELU layer-1 output)
#define OFF_AL1S  (OFF_H1E + NN*32)    // [NN*8]
#define OFF_AL1D  (OFF_AL1S + NN*8)    // [NN*8]
#define OFF_H2B   (OFF_AL1D + NN*8)    // [NN*16] bf16
#define OFF_AL2S  (OFF_H2B + NN*8)     // [NN]
#define OFF_AL2D  (OFF_AL2S + NN)      // [NN]

__device__ __forceinline__ float lrelu(float x) { return x >= 0.f ? x : NEG * x; }
__device__ __forceinline__ unsigned short f2bf(float x) {
    unsigned u = __float_as_uint(x);
    return (unsigned short)((u + 0x7FFF + ((u >> 16) & 1)) >> 16);   // RNE
}
__device__ __forceinline__ float bf2f(unsigned short b) {
    return __uint_as_float(((unsigned)b) << 16);
}

// ---------- CSR build ----------
__global__ __launch_bounds__(256) void k_hist(
    const int* __restrict__ edst, int* __restrict__ deg)
{
    int ei = blockIdx.x * 256 + threadIdx.x;
    if (ei >= NEDGE) return;
    int d = (ei < EE) ? edst[ei] : ei - EE;
    atomicAdd(&deg[d], 1);
}

__global__ __launch_bounds__(256) void k_scan1(
    const int* __restrict__ deg, int* __restrict__ tmp, int* __restrict__ bsum)
{
    __shared__ int s[256];
    int t = threadIdx.x;
    int i = blockIdx.x * 256 + t;
    int v = (i < NN) ? deg[i] : 0;
    s[t] = v;
    __syncthreads();
    for (int off = 1; off < 256; off <<= 1) {
        int u = (t >= off) ? s[t - off] : 0;
        __syncthreads();
        s[t] += u;
        __syncthreads();
    }
    if (i < NN) tmp[i] = s[t] - v;
    if (t == 255) bsum[blockIdx.x] = s[255];
}

__global__ __launch_bounds__(512) void k_scan2(int* __restrict__ bsum)
{
    __shared__ int s[512];
    int t = threadIdx.x;
    int v = (t < NBLK) ? bsum[t] : 0;
    s[t] = v;
    __syncthreads();
    for (int off = 1; off < 512; off <<= 1) {
        int u = (t >= off) ? s[t - off] : 0;
        __syncthreads();
        s[t] += u;
        __syncthreads();
    }
    bsum[t] = s[t] - v;
}

__global__ __launch_bounds__(256) void k_scan3(
    const int* __restrict__ tmp, const int* __restrict__ bsum,
    int* __restrict__ row)
{
    int i = blockIdx.x * 256 + threadIdx.x;
    if (i < NN) row[i] = tmp[i] + bsum[blockIdx.x];
    if (i == 0) row[NN] = NEDGE;
}

__global__ __launch_bounds__(256) void k_fill(
    const int* __restrict__ esrc, const int* __restrict__ edst,
    const int* __restrict__ row, int* __restrict__ cnt, int* __restrict__ adj)
{
    int ei = blockIdx.x * 256 + threadIdx.x;
    if (ei >= NEDGE) return;
    int s, d;
    if (ei < EE) { s = esrc[ei]; d = edst[ei]; } else { s = d = ei - EE; }
    int pos = row[d] + atomicAdd(&cnt[d], 1);
    adj[pos] = s;
}

// ---------- layer 1 GEMM: 64x64 tile, 4x4 register tile; bf16 value output ----------
__global__ __launch_bounds__(256) void k_gemm1(
    const float* __restrict__ x, const float* __restrict__ W1,
    const float* __restrict__ a1s, const float* __restrict__ a1d,
    unsigned short* __restrict__ h1b, float* __restrict__ al1s, float* __restrict__ al1d)
{
    __shared__ float sxT[32][68];
    __shared__ float sW[32][64];
    const int t = threadIdx.x;
    const int n0 = blockIdx.x * 64;
    const int tr = t >> 4, tc = t & 15;

    float acc[4][4] = {};

    for (int kc = 0; kc < 256; kc += 32) {
        __syncthreads();
        #pragma unroll
        for (int it = 0; it < 2; ++it) {
            int i = t + it * 256;
            int r = i >> 3, fj = i & 7;
            int n = n0 + r;
            float4 v = (n < NN) ? *(const float4*)(x + (size_t)n * FIN + kc + fj * 4)
                                : make_float4(0.f, 0.f, 0.f, 0.f);
            sxT[fj * 4 + 0][r] = v.x;
            sxT[fj * 4 + 1][r] = v.y;
            sxT[fj * 4 + 2][r] = v.z;
            sxT[fj * 4 + 3][r] = v.w;
        }
        #pragma unroll
        for (int it = 0; it < 2; ++it) {
            int i = t + it * 256;
            int r = i >> 4, fj = i & 15;
            *(float4*)&sW[r][fj * 4] = *(const float4*)(W1 + (size_t)(kc + r) * 64 + fj * 4);
        }
        __syncthreads();
        #pragma unroll
        for (int k = 0; k < 32; ++k) {
            float4 a = *(const float4*)&sxT[k][tr * 4];
            float4 b = *(const float4*)&sW[k][tc * 4];
            acc[0][0] += a.x * b.x; acc[0][1] += a.x * b.y; acc[0][2] += a.x * b.z; acc[0][3] += a.x * b.w;
            acc[1][0] += a.y * b.x; acc[1][1] += a.y * b.y; acc[1][2] += a.y * b.z; acc[1][3] += a.y * b.w;
            acc[2][0] += a.z * b.x; acc[2][1] += a.z * b.y; acc[2][2] += a.z * b.z; acc[2][3] += a.z * b.w;
            acc[3][0] += a.w * b.x; acc[3][1] += a.w * b.y; acc[3][2] += a.w * b.z; acc[3][3] += a.w * b.w;
        }
    }

    #pragma unroll
    for (int j = 0; j < 4; ++j) {
        int n = n0 + tr * 4 + j;
        if (n < NN) {
            ushort4 v = make_ushort4(f2bf(acc[j][0]), f2bf(acc[j][1]), f2bf(acc[j][2]), f2bf(acc[j][3]));
            *(ushort4*)(h1b + (size_t)n * 64 + tc * 4) = v;
        }
    }

    float sa[4], da[4];
    #pragma unroll
    for (int u = 0; u < 4; ++u) { sa[u] = a1s[tc * 4 + u]; da[u] = a1d[tc * 4 + u]; }
    #pragma unroll
    for (int j = 0; j < 4; ++j) {
        float vs = acc[j][0] * sa[0] + acc[j][1] * sa[1] + acc[j][2] * sa[2] + acc[j][3] * sa[3];
        float vd = acc[j][0] * da[0] + acc[j][1] * da[1] + acc[j][2] * da[2] + acc[j][3] * da[3];
        vs += __shfl_xor(vs, 1, 64);
        vd += __shfl_xor(vd, 1, 64);
        int n = n0 + tr * 4 + j;
        if (!(tc & 1) && n < NN) {
            al1s[n * 8 + (tc >> 1)] = vs;
            al1d[n * 8 + (tc >> 1)] = vd;
        }
    }
}

// ---------- layer 1 aggregation: exp-softmax (no max), bf16 gather, fused ELU ----------
__global__ __launch_bounds__(256) void k_agg1(
    const int* __restrict__ row, const int* __restrict__ adj,
    const float* __restrict__ al1s, const float* __restrict__ al1d,
    const unsigned short* __restrict__ h1b, const float* __restrict__ b1,
    unsigned short* __restrict__ h1e)
{
    const int wv = threadIdx.x >> 6, lane = threadIdx.x & 63;
    const int n = blockIdx.x * 4 + wv;
    const int h = lane >> 3;
    const float ald = al1d[n * 8 + h];
    const int r0 = row[n], r1 = row[n + 1];

    float dsum = 0.f, acc = 0.f;
    int i = r0;
    for (; i + 3 < r1; i += 4) {
        int s0 = adj[i], s1 = adj[i + 1], s2 = adj[i + 2], s3 = adj[i + 3];
        float w0 = __expf(lrelu(al1s[s0 * 8 + h] + ald));
        float w1 = __expf(lrelu(al1s[s1 * 8 + h] + ald));
        float w2 = __expf(lrelu(al1s[s2 * 8 + h] + ald));
        float w3 = __expf(lrelu(al1s[s3 * 8 + h] + ald));
        unsigned short u0 = h1b[(size_t)s0 * 64 + lane];
        unsigned short u1 = h1b[(size_t)s1 * 64 + lane];
        unsigned short u2 = h1b[(size_t)s2 * 64 + lane];
        unsigned short u3 = h1b[(size_t)s3 * 64 + lane];
        dsum += (w0 + w1) + (w2 + w3);
        acc  += (w0 * bf2f(u0) + w1 * bf2f(u1)) + (w2 * bf2f(u2) + w3 * bf2f(u3));
    }
    for (; i < r1; ++i) {
        int s0 = adj[i];
        float w0 = __expf(lrelu(al1s[s0 * 8 + h] + ald));
        dsum += w0;
        acc  += w0 * bf2f(h1b[(size_t)s0 * 64 + lane]);
    }
    float v = acc / dsum + b1[lane];
    v = v > 0.f ? v : __expf(v) - 1.f;       // ELU fused
    h1e[(size_t)n * 64 + lane] = f2bf(v);
}

// ---------- layer 2 GEMM: h2b = bf16(h1e @ W2), al2s/al2d logits ----------
__global__ __launch_bounds__(256) void k_gemm2(
    const unsigned short* __restrict__ h1e, const float* __restrict__ W2,
    const float* __restrict__ a2s, const float* __restrict__ a2d,
    unsigned short* __restrict__ h2b, float* __restrict__ al2s, float* __restrict__ al2d)
{
    __shared__ float sW[64 * 16];
    const int t = threadIdx.x;
    for (int i = t; i < 64 * 16; i += 256) sW[i] = W2[i];
    __syncthreads();
    const int n = blockIdx.x * 16 + (t >> 4);
    const int k = t & 15;
    if (n >= NN) return;
    const unsigned short* hr = h1e + (size_t)n * 64;
    float acc = 0.f;
    #pragma unroll
    for (int c = 0; c < 64; ++c) acc += bf2f(hr[c]) * sW[c * 16 + k];
    h2b[(size_t)n * 16 + k] = f2bf(acc);
    float vs = acc * a2s[k], vd = acc * a2d[k];
    #pragma unroll
    for (int off = 1; off < 16; off <<= 1) {
        vs += __shfl_xor(vs, off, 64);
        vd += __shfl_xor(vd, off, 64);
    }
    if (k == 0) { al2s[n] = vs; al2d[n] = vd; }
}

// ---------- layer 2 aggregation (exp-softmax, 4 edges x 16 ch per wave) + log_softmax ----------
__global__ __launch_bounds__(256) void k_agg2(
    const int* __restrict__ row, const int* __restrict__ adj,
    const float* __restrict__ al2s, const float* __restrict__ al2d,
    const unsigned short* __restrict__ h2b, const float* __restrict__ b2,
    float* __restrict__ out)
{
    const int wv = threadIdx.x >> 6, lane = threadIdx.x & 63;
    const int n = blockIdx.x * 4 + wv;
    const float ald = al2d[n];
    const int r0 = row[n], r1 = row[n + 1];

    const int k = lane & 15, j = lane >> 4;   // 4 edge-groups x 16 channels
    float dsum = 0.f, acc = 0.f;
    for (int i = r0 + j; i < r1; i += 4) {
        int s = adj[i];
        float w = __expf(lrelu(al2s[s] + ald));
        dsum += w;
        acc  += w * bf2f(h2b[(size_t)s * 16 + k]);
    }
    #pragma unroll
    for (int off = 16; off < 64; off <<= 1) {
        dsum += __shfl_xor(dsum, off, 64);
        acc  += __shfl_xor(acc, off, 64);
    }
    float v = acc / dsum + b2[k];
    float mx = v;
    #pragma unroll
    for (int off = 1; off < 16; off <<= 1) mx = fmaxf(mx, __shfl_xor(mx, off, 64));
    float se = __expf(v - mx);
    #pragma unroll
    for (int off = 1; off < 16; off <<= 1) se += __shfl_xor(se, off, 64);
    float ls = mx + __logf(se);
    if (j == 0) out[(size_t)n * 16 + k] = v - ls;
}

extern "C" void kernel_launch(void* const* d_in, const int* in_sizes, int n_in,
                              void* d_out, int out_size, void* d_ws, size_t ws_size,
                              hipStream_t stream)
{
    const float* x    = (const float*)d_in[0];
    const int*   eidx = (const int*)d_in[1];
    const float* W1   = (const float*)d_in[2];
    const float* a1s  = (const float*)d_in[3];
    const float* a1d  = (const float*)d_in[4];
    const float* b1   = (const float*)d_in[5];
    const float* W2   = (const float*)d_in[6];
    const float* a2s  = (const float*)d_in[7];
    const float* a2d  = (const float*)d_in[8];
    const float* b2   = (const float*)d_in[9];
    float* out = (float*)d_out;
    float* ws  = (float*)d_ws;

    const int* esrc = eidx;
    const int* edst = eidx + EE;

    int* deg  = (int*)(ws + OFF_DEG);
    int* cnt  = (int*)(ws + OFF_CNT);
    int* row  = (int*)(ws + OFF_ROW);
    int* tmp  = (int*)(ws + OFF_TMP);
    int* bsum = (int*)(ws + OFF_BSUM);
    int* adj  = (int*)(ws + OFF_ADJ);
    unsigned short* h1b = (unsigned short*)(ws + OFF_H1B);
    unsigned short* h1e = (unsigned short*)(ws + OFF_H1E);
    float* al1s  = ws + OFF_AL1S;
    float* al1d  = ws + OFF_AL1D;
    unsigned short* h2b = (unsigned short*)(ws + OFF_H2B);
    float* al2s  = ws + OFF_AL2S;
    float* al2d  = ws + OFF_AL2D;

    hipMemsetAsync(ws, 0, (size_t)NZERO_I * sizeof(int), stream);

    const int gE = (NEDGE + 255) / 256;
    k_hist <<<gE,   256, 0, stream>>>(edst, deg);
    k_scan1<<<NBLK, 256, 0, stream>>>(deg, tmp, bsum);
    k_scan2<<<1,    512, 0, stream>>>(bsum);
    k_scan3<<<NBLK, 256, 0, stream>>>(tmp, bsum, row);
    k_fill <<<gE,   256, 0, stream>>>(esrc, edst, row, cnt, adj);

    k_gemm1<<<(NN + 63) / 64, 256, 0, stream>>>(x, W1, a1s, a1d, h1b, al1s, al1d);
    k_agg1 <<<NN / 4, 256, 0, stream>>>(row, adj, al1s, al1d, h1b, b1, h1e);
    k_gemm2<<<NN / 16, 256, 0, stream>>>(h1e, W2, a2s, a2d, h2b, al2s, al2d);
    k_agg2 <<<NN / 4, 256, 0, stream>>>(row, adj, al2s, al2d, h2b, b2, out);
}

// Round 7
// 394.492 us; speedup vs baseline: 1.4634x; 1.2892x over previous
//
#include <hip/hip_runtime.h>
#include <math.h>

#define NN   100000
#define EE   1600000
#define FIN  256
#define NCLS 16
#define NEG  0.2f

#define NEDGE (EE + NN)     // with self-loops
#define WBKT  256           // dsts per bucket
#define NBKT  ((NN + WBKT - 1) / WBKT)   // 391
#define CAP   5120          // per-bucket capacity (mean 4352, +12 sigma)
#define ABLK  4096          // edges per binA block
#define NABLK ((NEDGE + ABLK - 1) / ABLK)  // 416

// ---- workspace layout (4-byte element offsets) ----
#define OFF_GCNT  0                          // [392] zeroed each call
#define OFF_BASE  392                        // [392]
#define OFF_ROW   784                        // [NN+1]
#define OFF_BKT   100788                     // [NBKT*CAP] packed (src<<8)|dlow
#define OFF_ADJ   (OFF_BKT + NBKT*CAP)       // [NEDGE]
#define OFF_H1B   (OFF_ADJ + NEDGE)          // [NN*64] bf16 (pre-attn values)
#define OFF_H1E   (OFF_H1B + NN*32)          // [NN*64] bf16 (post-ELU)
#define OFF_AL1S  (OFF_H1E + NN*32)          // [NN*8]
#define OFF_AL1D  (OFF_AL1S + NN*8)          // [NN*8]
#define OFF_H2B   (OFF_AL1D + NN*8)          // [NN*16] bf16
#define OFF_AL2S  (OFF_H2B + NN*8)           // [NN]
#define OFF_AL2D  (OFF_AL2S + NN)            // [NN]

__device__ __forceinline__ float lrelu(float x) { return x >= 0.f ? x : NEG * x; }
__device__ __forceinline__ unsigned short f2bf(float x) {
    unsigned u = __float_as_uint(x);
    return (unsigned short)((u + 0x7FFF + ((u >> 16) & 1)) >> 16);   // RNE
}
__device__ __forceinline__ float bf2f(unsigned short b) {
    return __uint_as_float(((unsigned)b) << 16);
}

// ---------- CSR build, phase A: bin edges by dst>>8 ----------
__global__ __launch_bounds__(256) void k_binA(
    const int* __restrict__ esrc, const int* __restrict__ edst,
    int* __restrict__ gcnt, unsigned* __restrict__ bkt)
{
    __shared__ int lcnt[NBKT];
    __shared__ int lbase[NBKT];
    const int t = threadIdx.x;
    const int e0 = blockIdx.x * ABLK;
    for (int i = t; i < NBKT; i += 256) lcnt[i] = 0;
    __syncthreads();

    unsigned wrd[16];
    unsigned short bb[16], ll[16];
    #pragma unroll
    for (int j = 0; j < 16; ++j) {
        int ei = e0 + j * 256 + t;
        bb[j] = 0xFFFFu;
        if (ei < NEDGE) {
            int s, d;
            if (ei < EE) { s = esrc[ei]; d = edst[ei]; } else { s = d = ei - EE; }
            int b = d >> 8;
            wrd[j] = ((unsigned)s << 8) | (unsigned)(d & 255);
            bb[j] = (unsigned short)b;
            ll[j] = (unsigned short)atomicAdd(&lcnt[b], 1);
        }
    }
    __syncthreads();
    for (int i = t; i < NBKT; i += 256)
        lbase[i] = lcnt[i] ? atomicAdd(&gcnt[i], lcnt[i]) : 0;
    __syncthreads();
    #pragma unroll
    for (int j = 0; j < 16; ++j) {
        if (bb[j] != 0xFFFFu) {
            int b = bb[j];
            bkt[(size_t)b * CAP + lbase[b] + ll[j]] = wrd[j];
        }
    }
}

// ---------- CSR build, phase B: scan bucket counts -> bases ----------
__global__ __launch_bounds__(512) void k_scanB(
    const int* __restrict__ gcnt, int* __restrict__ base, int* __restrict__ row)
{
    __shared__ int s[512];
    int t = threadIdx.x;
    int v = (t < NBKT) ? gcnt[t] : 0;
    s[t] = v;
    __syncthreads();
    for (int off = 1; off < 512; off <<= 1) {
        int u = (t >= off) ? s[t - off] : 0;
        __syncthreads();
        s[t] += u;
        __syncthreads();
    }
    if (t <= NBKT) base[t] = s[t] - v;   // exclusive; base[NBKT] = NEDGE
    if (t == 0) row[NN] = NEDGE;
}

// ---------- CSR build, phase C: per-bucket local sort -> row + adj ----------
__global__ __launch_bounds__(256) void k_binC(
    const int* __restrict__ gcnt, const int* __restrict__ base,
    const unsigned* __restrict__ bkt, int* __restrict__ row, int* __restrict__ adj)
{
    __shared__ unsigned wd[CAP];          // 20 KB stage
    __shared__ int hist[256], pref[256], cnt2[256];
    const int g = blockIdx.x, t = threadIdx.x;
    const int cn = gcnt[g], bs = base[g];
    hist[t] = 0; cnt2[t] = 0;
    __syncthreads();
    for (int i = t; i < cn; i += 256) {
        unsigned w = bkt[(size_t)g * CAP + i];
        wd[i] = w;
        atomicAdd(&hist[w & 255], 1);
    }
    __syncthreads();
    int v = hist[t];
    pref[t] = v;
    __syncthreads();
    for (int off = 1; off < 256; off <<= 1) {
        int u = (t >= off) ? pref[t - off] : 0;
        __syncthreads();
        pref[t] += u;
        __syncthreads();
    }
    int ex = pref[t] - v;                 // exclusive local prefix
    int n = g * 256 + t;
    if (n < NN) row[n] = bs + ex;
    pref[t] = ex;
    __syncthreads();
    for (int i = t; i < cn; i += 256) {
        unsigned w = wd[i];
        int dl = w & 255;
        int p = atomicAdd(&cnt2[dl], 1);
        adj[bs + pref[dl] + p] = (int)(w >> 8);
    }
}

// ---------- layer 1 GEMM: 64x64 tile, 4x4 register tile; bf16 value output ----------
__global__ __launch_bounds__(256) void k_gemm1(
    const float* __restrict__ x, const float* __restrict__ W1,
    const float* __restrict__ a1s, const float* __restrict__ a1d,
    unsigned short* __restrict__ h1b, float* __restrict__ al1s, float* __restrict__ al1d)
{
    __shared__ float sxT[32][68];
    __shared__ float sW[32][64];
    const int t = threadIdx.x;
    const int n0 = blockIdx.x * 64;
    const int tr = t >> 4, tc = t & 15;

    float acc[4][4] = {};

    for (int kc = 0; kc < 256; kc += 32) {
        __syncthreads();
        #pragma unroll
        for (int it = 0; it < 2; ++it) {
            int i = t + it * 256;
            int r = i >> 3, fj = i & 7;
            int n = n0 + r;
            float4 v = (n < NN) ? *(const float4*)(x + (size_t)n * FIN + kc + fj * 4)
                                : make_float4(0.f, 0.f, 0.f, 0.f);
            sxT[fj * 4 + 0][r] = v.x;
            sxT[fj * 4 + 1][r] = v.y;
            sxT[fj * 4 + 2][r] = v.z;
            sxT[fj * 4 + 3][r] = v.w;
        }
        #pragma unroll
        for (int it = 0; it < 2; ++it) {
            int i = t + it * 256;
            int r = i >> 4, fj = i & 15;
            *(float4*)&sW[r][fj * 4] = *(const float4*)(W1 + (size_t)(kc + r) * 64 + fj * 4);
        }
        __syncthreads();
        #pragma unroll
        for (int k = 0; k < 32; ++k) {
            float4 a = *(const float4*)&sxT[k][tr * 4];
            float4 b = *(const float4*)&sW[k][tc * 4];
            acc[0][0] += a.x * b.x; acc[0][1] += a.x * b.y; acc[0][2] += a.x * b.z; acc[0][3] += a.x * b.w;
            acc[1][0] += a.y * b.x; acc[1][1] += a.y * b.y; acc[1][2] += a.y * b.z; acc[1][3] += a.y * b.w;
            acc[2][0] += a.z * b.x; acc[2][1] += a.z * b.y; acc[2][2] += a.z * b.z; acc[2][3] += a.z * b.w;
            acc[3][0] += a.w * b.x; acc[3][1] += a.w * b.y; acc[3][2] += a.w * b.z; acc[3][3] += a.w * b.w;
        }
    }

    #pragma unroll
    for (int j = 0; j < 4; ++j) {
        int n = n0 + tr * 4 + j;
        if (n < NN) {
            ushort4 v = make_ushort4(f2bf(acc[j][0]), f2bf(acc[j][1]), f2bf(acc[j][2]), f2bf(acc[j][3]));
            *(ushort4*)(h1b + (size_t)n * 64 + tc * 4) = v;
        }
    }

    float sa[4], da[4];
    #pragma unroll
    for (int u = 0; u < 4; ++u) { sa[u] = a1s[tc * 4 + u]; da[u] = a1d[tc * 4 + u]; }
    #pragma unroll
    for (int j = 0; j < 4; ++j) {
        float vs = acc[j][0] * sa[0] + acc[j][1] * sa[1] + acc[j][2] * sa[2] + acc[j][3] * sa[3];
        float vd = acc[j][0] * da[0] + acc[j][1] * da[1] + acc[j][2] * da[2] + acc[j][3] * da[3];
        vs += __shfl_xor(vs, 1, 64);
        vd += __shfl_xor(vd, 1, 64);
        int n = n0 + tr * 4 + j;
        if (!(tc & 1) && n < NN) {
            al1s[n * 8 + (tc >> 1)] = vs;
            al1d[n * 8 + (tc >> 1)] = vd;
        }
    }
}

// ---------- layer 1 aggregation: exp-softmax (no max), bf16 gather, fused ELU ----------
__global__ __launch_bounds__(256) void k_agg1(
    const int* __restrict__ row, const int* __restrict__ adj,
    const float* __restrict__ al1s, const float* __restrict__ al1d,
    const unsigned short* __restrict__ h1b, const float* __restrict__ b1,
    unsigned short* __restrict__ h1e)
{
    const int wv = threadIdx.x >> 6, lane = threadIdx.x & 63;
    const int n = blockIdx.x * 4 + wv;
    const int h = lane >> 3;
    const float ald = al1d[n * 8 + h];
    const int r0 = row[n], r1 = row[n + 1];

    float dsum = 0.f, acc = 0.f;
    int i = r0;
    for (; i + 3 < r1; i += 4) {
        int s0 = adj[i], s1 = adj[i + 1], s2 = adj[i + 2], s3 = adj[i + 3];
        float w0 = __expf(lrelu(al1s[s0 * 8 + h] + ald));
        float w1 = __expf(lrelu(al1s[s1 * 8 + h] + ald));
        float w2 = __expf(lrelu(al1s[s2 * 8 + h] + ald));
        float w3 = __expf(lrelu(al1s[s3 * 8 + h] + ald));
        unsigned short u0 = h1b[(size_t)s0 * 64 + lane];
        unsigned short u1 = h1b[(size_t)s1 * 64 + lane];
        unsigned short u2 = h1b[(size_t)s2 * 64 + lane];
        unsigned short u3 = h1b[(size_t)s3 * 64 + lane];
        dsum += (w0 + w1) + (w2 + w3);
        acc  += (w0 * bf2f(u0) + w1 * bf2f(u1)) + (w2 * bf2f(u2) + w3 * bf2f(u3));
    }
    for (; i < r1; ++i) {
        int s0 = adj[i];
        float w0 = __expf(lrelu(al1s[s0 * 8 + h] + ald));
        dsum += w0;
        acc  += w0 * bf2f(h1b[(size_t)s0 * 64 + lane]);
    }
    float v = acc / dsum + b1[lane];
    v = v > 0.f ? v : __expf(v) - 1.f;       // ELU fused
    h1e[(size_t)n * 64 + lane] = f2bf(v);
}

// ---------- layer 2 GEMM: h2b = bf16(h1e @ W2), al2s/al2d logits ----------
__global__ __launch_bounds__(256) void k_gemm2(
    const unsigned short* __restrict__ h1e, const float* __restrict__ W2,
    const float* __restrict__ a2s, const float* __restrict__ a2d,
    unsigned short* __restrict__ h2b, float* __restrict__ al2s, float* __restrict__ al2d)
{
    __shared__ float sW[64 * 16];
    const int t = threadIdx.x;
    for (int i = t; i < 64 * 16; i += 256) sW[i] = W2[i];
    __syncthreads();
    const int n = blockIdx.x * 16 + (t >> 4);
    const int k = t & 15;
    if (n >= NN) return;
    const unsigned short* hr = h1e + (size_t)n * 64;
    float acc = 0.f;
    #pragma unroll
    for (int c = 0; c < 64; ++c) acc += bf2f(hr[c]) * sW[c * 16 + k];
    h2b[(size_t)n * 16 + k] = f2bf(acc);
    float vs = acc * a2s[k], vd = acc * a2d[k];
    #pragma unroll
    for (int off = 1; off < 16; off <<= 1) {
        vs += __shfl_xor(vs, off, 64);
        vd += __shfl_xor(vd, off, 64);
    }
    if (k == 0) { al2s[n] = vs; al2d[n] = vd; }
}

// ---------- layer 2 aggregation (exp-softmax) + log_softmax ----------
__global__ __launch_bounds__(256) void k_agg2(
    const int* __restrict__ row, const int* __restrict__ adj,
    const float* __restrict__ al2s, const float* __restrict__ al2d,
    const unsigned short* __restrict__ h2b, const float* __restrict__ b2,
    float* __restrict__ out)
{
    const int wv = threadIdx.x >> 6, lane = threadIdx.x & 63;
    const int n = blockIdx.x * 4 + wv;
    const float ald = al2d[n];
    const int r0 = row[n], r1 = row[n + 1];

    const int k = lane & 15, j = lane >> 4;   // 4 edge-groups x 16 channels
    float dsum = 0.f, acc = 0.f;
    for (int i = r0 + j; i < r1; i += 4) {
        int s = adj[i];
        float w = __expf(lrelu(al2s[s] + ald));
        dsum += w;
        acc  += w * bf2f(h2b[(size_t)s * 16 + k]);
    }
    #pragma unroll
    for (int off = 16; off < 64; off <<= 1) {
        dsum += __shfl_xor(dsum, off, 64);
        acc  += __shfl_xor(acc, off, 64);
    }
    float v = acc / dsum + b2[k];
    float mx = v;
    #pragma unroll
    for (int off = 1; off < 16; off <<= 1) mx = fmaxf(mx, __shfl_xor(mx, off, 64));
    float se = __expf(v - mx);
    #pragma unroll
    for (int off = 1; off < 16; off <<= 1) se += __shfl_xor(se, off, 64);
    float ls = mx + __logf(se);
    if (j == 0) out[(size_t)n * 16 + k] = v - ls;
}

extern "C" void kernel_launch(void* const* d_in, const int* in_sizes, int n_in,
                              void* d_out, int out_size, void* d_ws, size_t ws_size,
                              hipStream_t stream)
{
    const float* x    = (const float*)d_in[0];
    const int*   eidx = (const int*)d_in[1];
    const float* W1   = (const float*)d_in[2];
    const float* a1s  = (const float*)d_in[3];
    const float* a1d  = (const float*)d_in[4];
    const float* b1   = (const float*)d_in[5];
    const float* W2   = (const float*)d_in[6];
    const float* a2s  = (const float*)d_in[7];
    const float* a2d  = (const float*)d_in[8];
    const float* b2   = (const float*)d_in[9];
    float* out = (float*)d_out;
    float* ws  = (float*)d_ws;

    const int* esrc = eidx;
    const int* edst = eidx + EE;

    int* gcnt = (int*)(ws + OFF_GCNT);
    int* base = (int*)(ws + OFF_BASE);
    int* row  = (int*)(ws + OFF_ROW);
    unsigned* bkt = (unsigned*)(ws + OFF_BKT);
    int* adj  = (int*)(ws + OFF_ADJ);
    unsigned short* h1b = (unsigned short*)(ws + OFF_H1B);
    unsigned short* h1e = (unsigned short*)(ws + OFF_H1E);
    float* al1s  = ws + OFF_AL1S;
    float* al1d  = ws + OFF_AL1D;
    unsigned short* h2b = (unsigned short*)(ws + OFF_H2B);
    float* al2s  = ws + OFF_AL2S;
    float* al2d  = ws + OFF_AL2D;

    hipMemsetAsync(gcnt, 0, 392 * sizeof(int), stream);

    k_binA <<<NABLK, 256, 0, stream>>>(esrc, edst, gcnt, bkt);
    k_scanB<<<1,     512, 0, stream>>>(gcnt, base, row);
    k_binC <<<NBKT,  256, 0, stream>>>(gcnt, base, bkt, row, adj);

    k_gemm1<<<(NN + 63) / 64, 256, 0, stream>>>(x, W1, a1s, a1d, h1b, al1s, al1d);
    k_agg1 <<<NN / 4, 256, 0, stream>>>(row, adj, al1s, al1d, h1b, b1, h1e);
    k_gemm2<<<NN / 16, 256, 0, stream>>>(h1e, W2, a2s, a2d, h2b, al2s, al2d);
    k_agg2 <<<NN / 4, 256, 0, stream>>>(row, adj, al2s, al2d, h2b, b2, out);
}

// Round 8
// 390.024 us; speedup vs baseline: 1.4802x; 1.0115x over previous
//
#include <hip/hip_runtime.h>
#include <math.h>

#define NN   100000
#define EE   1600000
#define FIN  256
#define NCLS 16
#define NEG  0.2f

#define NEDGE (EE + NN)     // with self-loops
#define WBKT  256           // dsts per bucket
#define NBKT  ((NN + WBKT - 1) / WBKT)   // 391
#define CAP   5120          // per-bucket capacity (mean 4352)
#define ABLK  4096          // edges per binA block
#define NABLK ((NEDGE + ABLK - 1) / ABLK)  // 416

// ---- workspace layout (4-byte element offsets) ----
#define OFF_GCNT  0                          // [392] zeroed each call
#define OFF_BASE  392                        // [392]
#define OFF_ROW   784                        // [NN+1]
#define OFF_BKT   100788                     // [NBKT*CAP] packed (src<<8)|dlow
#define OFF_ADJ   (OFF_BKT + NBKT*CAP)       // [NEDGE]
#define OFF_H1B   (OFF_ADJ + NEDGE)          // [NN*64] bf16 (pre-attn values)
#define OFF_H1E   (OFF_H1B + NN*32)          // [NN*64] bf16 (post-ELU)
#define OFF_AL1S  (OFF_H1E + NN*32)          // [NN*8]
#define OFF_AL1D  (OFF_AL1S + NN*8)          // [NN*8]
#define OFF_H2B   (OFF_AL1D + NN*8)          // [NN*16] bf16
#define OFF_AL2S  (OFF_H2B + NN*8)           // [NN]
#define OFF_AL2D  (OFF_AL2S + NN)            // [NN]

__device__ __forceinline__ float lrelu(float x) { return x >= 0.f ? x : NEG * x; }
__device__ __forceinline__ unsigned short f2bf(float x) {
    unsigned u = __float_as_uint(x);
    return (unsigned short)((u + 0x7FFF + ((u >> 16) & 1)) >> 16);   // RNE
}
__device__ __forceinline__ float bf2f(unsigned short b) {
    return __uint_as_float(((unsigned)b) << 16);
}
__device__ __forceinline__ float bflo(unsigned u) { return __uint_as_float(u << 16); }
__device__ __forceinline__ float bfhi(unsigned u) { return __uint_as_float(u & 0xFFFF0000u); }

// ---------- CSR build, phase A: bin edges by dst>>8 ----------
__global__ __launch_bounds__(256) void k_binA(
    const int* __restrict__ esrc, const int* __restrict__ edst,
    int* __restrict__ gcnt, unsigned* __restrict__ bkt)
{
    __shared__ int lcnt[NBKT];
    __shared__ int lbase[NBKT];
    const int t = threadIdx.x;
    const int e0 = blockIdx.x * ABLK;
    for (int i = t; i < NBKT; i += 256) lcnt[i] = 0;
    __syncthreads();

    unsigned wrd[16];
    unsigned short bb[16], ll[16];
    #pragma unroll
    for (int j = 0; j < 16; ++j) {
        int ei = e0 + j * 256 + t;
        bb[j] = 0xFFFFu;
        if (ei < NEDGE) {
            int s, d;
            if (ei < EE) { s = esrc[ei]; d = edst[ei]; } else { s = d = ei - EE; }
            int b = d >> 8;
            wrd[j] = ((unsigned)s << 8) | (unsigned)(d & 255);
            bb[j] = (unsigned short)b;
            ll[j] = (unsigned short)atomicAdd(&lcnt[b], 1);
        }
    }
    __syncthreads();
    for (int i = t; i < NBKT; i += 256)
        lbase[i] = lcnt[i] ? atomicAdd(&gcnt[i], lcnt[i]) : 0;
    __syncthreads();
    #pragma unroll
    for (int j = 0; j < 16; ++j) {
        if (bb[j] != 0xFFFFu) {
            int b = bb[j];
            bkt[(size_t)b * CAP + lbase[b] + ll[j]] = wrd[j];
        }
    }
}

// ---------- CSR build, phase B: scan bucket counts -> bases ----------
__global__ __launch_bounds__(512) void k_scanB(
    const int* __restrict__ gcnt, int* __restrict__ base, int* __restrict__ row)
{
    __shared__ int s[512];
    int t = threadIdx.x;
    int v = (t < NBKT) ? gcnt[t] : 0;
    s[t] = v;
    __syncthreads();
    for (int off = 1; off < 512; off <<= 1) {
        int u = (t >= off) ? s[t - off] : 0;
        __syncthreads();
        s[t] += u;
        __syncthreads();
    }
    if (t <= NBKT) base[t] = s[t] - v;   // exclusive; base[NBKT] = NEDGE
    if (t == 0) row[NN] = NEDGE;
}

// ---------- CSR build, phase C: per-bucket local sort -> row + adj ----------
__global__ __launch_bounds__(256) void k_binC(
    const int* __restrict__ gcnt, const int* __restrict__ base,
    const unsigned* __restrict__ bkt, int* __restrict__ row, int* __restrict__ adj)
{
    __shared__ unsigned wd[CAP];          // 20 KB stage
    __shared__ int hist[256], pref[256], cnt2[256];
    const int g = blockIdx.x, t = threadIdx.x;
    const int cn = gcnt[g], bs = base[g];
    hist[t] = 0; cnt2[t] = 0;
    __syncthreads();
    for (int i = t; i < cn; i += 256) {
        unsigned w = bkt[(size_t)g * CAP + i];
        wd[i] = w;
        atomicAdd(&hist[w & 255], 1);
    }
    __syncthreads();
    int v = hist[t];
    pref[t] = v;
    __syncthreads();
    for (int off = 1; off < 256; off <<= 1) {
        int u = (t >= off) ? pref[t - off] : 0;
        __syncthreads();
        pref[t] += u;
        __syncthreads();
    }
    int ex = pref[t] - v;                 // exclusive local prefix
    int n = g * 256 + t;
    if (n < NN) row[n] = bs + ex;
    pref[t] = ex;
    __syncthreads();
    for (int i = t; i < cn; i += 256) {
        unsigned w = wd[i];
        int dl = w & 255;
        int p = atomicAdd(&cnt2[dl], 1);
        adj[bs + pref[dl] + p] = (int)(w >> 8);
    }
}

// ---------- layer 1 GEMM: 64x64 tile, 4x4 register tile; bf16 value output ----------
__global__ __launch_bounds__(256) void k_gemm1(
    const float* __restrict__ x, const float* __restrict__ W1,
    const float* __restrict__ a1s, const float* __restrict__ a1d,
    unsigned short* __restrict__ h1b, float* __restrict__ al1s, float* __restrict__ al1d)
{
    __shared__ float sxT[32][68];
    __shared__ float sW[32][64];
    const int t = threadIdx.x;
    const int n0 = blockIdx.x * 64;
    const int tr = t >> 4, tc = t & 15;

    float acc[4][4] = {};

    for (int kc = 0; kc < 256; kc += 32) {
        __syncthreads();
        #pragma unroll
        for (int it = 0; it < 2; ++it) {
            int i = t + it * 256;
            int r = i >> 3, fj = i & 7;
            int n = n0 + r;
            float4 v = (n < NN) ? *(const float4*)(x + (size_t)n * FIN + kc + fj * 4)
                                : make_float4(0.f, 0.f, 0.f, 0.f);
            sxT[fj * 4 + 0][r] = v.x;
            sxT[fj * 4 + 1][r] = v.y;
            sxT[fj * 4 + 2][r] = v.z;
            sxT[fj * 4 + 3][r] = v.w;
        }
        #pragma unroll
        for (int it = 0; it < 2; ++it) {
            int i = t + it * 256;
            int r = i >> 4, fj = i & 15;
            *(float4*)&sW[r][fj * 4] = *(const float4*)(W1 + (size_t)(kc + r) * 64 + fj * 4);
        }
        __syncthreads();
        #pragma unroll
        for (int k = 0; k < 32; ++k) {
            float4 a = *(const float4*)&sxT[k][tr * 4];
            float4 b = *(const float4*)&sW[k][tc * 4];
            acc[0][0] += a.x * b.x; acc[0][1] += a.x * b.y; acc[0][2] += a.x * b.z; acc[0][3] += a.x * b.w;
            acc[1][0] += a.y * b.x; acc[1][1] += a.y * b.y; acc[1][2] += a.y * b.z; acc[1][3] += a.y * b.w;
            acc[2][0] += a.z * b.x; acc[2][1] += a.z * b.y; acc[2][2] += a.z * b.z; acc[2][3] += a.z * b.w;
            acc[3][0] += a.w * b.x; acc[3][1] += a.w * b.y; acc[3][2] += a.w * b.z; acc[3][3] += a.w * b.w;
        }
    }

    #pragma unroll
    for (int j = 0; j < 4; ++j) {
        int n = n0 + tr * 4 + j;
        if (n < NN) {
            ushort4 v = make_ushort4(f2bf(acc[j][0]), f2bf(acc[j][1]), f2bf(acc[j][2]), f2bf(acc[j][3]));
            *(ushort4*)(h1b + (size_t)n * 64 + tc * 4) = v;
        }
    }

    float sa[4], da[4];
    #pragma unroll
    for (int u = 0; u < 4; ++u) { sa[u] = a1s[tc * 4 + u]; da[u] = a1d[tc * 4 + u]; }
    #pragma unroll
    for (int j = 0; j < 4; ++j) {
        float vs = acc[j][0] * sa[0] + acc[j][1] * sa[1] + acc[j][2] * sa[2] + acc[j][3] * sa[3];
        float vd = acc[j][0] * da[0] + acc[j][1] * da[1] + acc[j][2] * da[2] + acc[j][3] * da[3];
        vs += __shfl_xor(vs, 1, 64);
        vd += __shfl_xor(vd, 1, 64);
        int n = n0 + tr * 4 + j;
        if (!(tc & 1) && n < NN) {
            al1s[n * 8 + (tc >> 1)] = vs;
            al1d[n * 8 + (tc >> 1)] = vd;
        }
    }
}

// ---------- layer 1 aggregation: 2 edges x 32 chpair-lanes, packed bf16x2 ----------
__global__ __launch_bounds__(256) void k_agg1(
    const int* __restrict__ row, const int* __restrict__ adj,
    const float* __restrict__ al1s, const float* __restrict__ al1d,
    const unsigned* __restrict__ h1b2, const float* __restrict__ b1,
    unsigned* __restrict__ h1e2)
{
    const int wv = threadIdx.x >> 6, lane = threadIdx.x & 63;
    const int n = blockIdx.x * 4 + wv;
    const int half = lane >> 5;        // which edge of the pair
    const int cp   = lane & 31;        // channel pair -> channels 2cp, 2cp+1
    const int h    = cp >> 2;          // head
    const float ald = al1d[n * 8 + h];
    const int r0 = row[n], r1 = row[n + 1];

    float dsum = 0.f, ax = 0.f, ay = 0.f;
    int i = r0;
    for (; i + 3 < r1; i += 4) {
        int i0 = i + half, i1 = i + 2 + half;
        int s0 = adj[i0], s1 = adj[i1];
        float w0 = __expf(lrelu(al1s[s0 * 8 + h] + ald));
        float w1 = __expf(lrelu(al1s[s1 * 8 + h] + ald));
        unsigned u0 = h1b2[s0 * 32 + cp];
        unsigned u1 = h1b2[s1 * 32 + cp];
        dsum += w0 + w1;
        ax += w0 * bflo(u0) + w1 * bflo(u1);
        ay += w0 * bfhi(u0) + w1 * bfhi(u1);
    }
    for (; i < r1; i += 2) {
        int i0 = i + half;
        bool act = i0 < r1;
        int s0 = adj[act ? i0 : r0];
        float w0 = act ? __expf(lrelu(al1s[s0 * 8 + h] + ald)) : 0.f;
        unsigned u0 = h1b2[s0 * 32 + cp];
        dsum += w0;
        ax += w0 * bflo(u0);
        ay += w0 * bfhi(u0);
    }
    dsum += __shfl_xor(dsum, 32, 64);
    ax   += __shfl_xor(ax, 32, 64);
    ay   += __shfl_xor(ay, 32, 64);

    float inv = 1.f / dsum;
    float vx = ax * inv + b1[cp * 2];
    float vy = ay * inv + b1[cp * 2 + 1];
    vx = vx > 0.f ? vx : __expf(vx) - 1.f;   // ELU fused
    vy = vy > 0.f ? vy : __expf(vy) - 1.f;
    if (half == 0)
        h1e2[n * 32 + cp] = (unsigned)f2bf(vx) | ((unsigned)f2bf(vy) << 16);
}

// ---------- layer 2 GEMM: h2b = bf16(h1e @ W2), al2s/al2d logits ----------
__global__ __launch_bounds__(256) void k_gemm2(
    const unsigned short* __restrict__ h1e, const float* __restrict__ W2,
    const float* __restrict__ a2s, const float* __restrict__ a2d,
    unsigned short* __restrict__ h2b, float* __restrict__ al2s, float* __restrict__ al2d)
{
    __shared__ float sW[64 * 16];
    const int t = threadIdx.x;
    for (int i = t; i < 64 * 16; i += 256) sW[i] = W2[i];
    __syncthreads();
    const int n = blockIdx.x * 16 + (t >> 4);
    const int k = t & 15;
    if (n >= NN) return;
    const unsigned short* hr = h1e + (size_t)n * 64;
    float acc = 0.f;
    #pragma unroll
    for (int c = 0; c < 64; ++c) acc += bf2f(hr[c]) * sW[c * 16 + k];
    h2b[(size_t)n * 16 + k] = f2bf(acc);
    float vs = acc * a2s[k], vd = acc * a2d[k];
    #pragma unroll
    for (int off = 1; off < 16; off <<= 1) {
        vs += __shfl_xor(vs, off, 64);
        vd += __shfl_xor(vd, off, 64);
    }
    if (k == 0) { al2s[n] = vs; al2d[n] = vd; }
}

// ---------- layer 2 aggregation: 8 edges x 8 chpair-lanes, packed ----------
__global__ __launch_bounds__(256) void k_agg2(
    const int* __restrict__ row, const int* __restrict__ adj,
    const float* __restrict__ al2s, const float* __restrict__ al2d,
    const unsigned* __restrict__ h2b2, const float* __restrict__ b2,
    float* __restrict__ out)
{
    const int wv = threadIdx.x >> 6, lane = threadIdx.x & 63;
    const int n = blockIdx.x * 4 + wv;
    const float ald = al2d[n];
    const int r0 = row[n], r1 = row[n + 1];

    const int j = lane >> 3;    // edge slot 0..7
    const int c = lane & 7;     // channel pair -> channels 2c, 2c+1
    float dsum = 0.f, ax = 0.f, ay = 0.f;
    for (int i = r0; i < r1; i += 8) {
        int i0 = i + j;
        bool act = i0 < r1;
        int s = adj[act ? i0 : r0];
        float w = act ? __expf(lrelu(al2s[s] + ald)) : 0.f;
        unsigned u = h2b2[s * 8 + c];
        dsum += w;
        ax += w * bflo(u);
        ay += w * bfhi(u);
    }
    #pragma unroll
    for (int off = 8; off < 64; off <<= 1) {
        dsum += __shfl_xor(dsum, off, 64);
        ax   += __shfl_xor(ax, off, 64);
        ay   += __shfl_xor(ay, off, 64);
    }
    float inv = 1.f / dsum;
    float vx = ax * inv + b2[c * 2];
    float vy = ay * inv + b2[c * 2 + 1];

    // log_softmax over 16 channels = 8 lanes x 2
    float mx = fmaxf(vx, vy);
    #pragma unroll
    for (int off = 1; off < 8; off <<= 1) mx = fmaxf(mx, __shfl_xor(mx, off, 64));
    float se = __expf(vx - mx) + __expf(vy - mx);
    #pragma unroll
    for (int off = 1; off < 8; off <<= 1) se += __shfl_xor(se, off, 64);
    float ls = mx + __logf(se);
    if (j == 0)
        *(float2*)(out + (size_t)n * 16 + c * 2) = make_float2(vx - ls, vy - ls);
}

extern "C" void kernel_launch(void* const* d_in, const int* in_sizes, int n_in,
                              void* d_out, int out_size, void* d_ws, size_t ws_size,
                              hipStream_t stream)
{
    const float* x    = (const float*)d_in[0];
    const int*   eidx = (const int*)d_in[1];
    const float* W1   = (const float*)d_in[2];
    const float* a1s  = (const float*)d_in[3];
    const float* a1d  = (const float*)d_in[4];
    const float* b1   = (const float*)d_in[5];
    const float* W2   = (const float*)d_in[6];
    const float* a2s  = (const float*)d_in[7];
    const float* a2d  = (const float*)d_in[8];
    const float* b2   = (const float*)d_in[9];
    float* out = (float*)d_out;
    float* ws  = (float*)d_ws;

    const int* esrc = eidx;
    const int* edst = eidx + EE;

    int* gcnt = (int*)(ws + OFF_GCNT);
    int* base = (int*)(ws + OFF_BASE);
    int* row  = (int*)(ws + OFF_ROW);
    unsigned* bkt = (unsigned*)(ws + OFF_BKT);
    int* adj  = (int*)(ws + OFF_ADJ);
    unsigned short* h1b = (unsigned short*)(ws + OFF_H1B);
    unsigned short* h1e = (unsigned short*)(ws + OFF_H1E);
    float* al1s  = ws + OFF_AL1S;
    float* al1d  = ws + OFF_AL1D;
    unsigned short* h2b = (unsigned short*)(ws + OFF_H2B);
    float* al2s  = ws + OFF_AL2S;
    float* al2d  = ws + OFF_AL2D;

    hipMemsetAsync(gcnt, 0, 392 * sizeof(int), stream);

    k_binA <<<NABLK, 256, 0, stream>>>(esrc, edst, gcnt, bkt);
    k_scanB<<<1,     512, 0, stream>>>(gcnt, base, row);
    k_binC <<<NBKT,  256, 0, stream>>>(gcnt, base, bkt, row, adj);

    k_gemm1<<<(NN + 63) / 64, 256, 0, stream>>>(x, W1, a1s, a1d, h1b, al1s, al1d);
    k_agg1 <<<NN / 4, 256, 0, stream>>>(row, adj, al1s, al1d, (const unsigned*)h1b, b1, (unsigned*)h1e);
    k_gemm2<<<NN / 16, 256, 0, stream>>>(h1e, W2, a2s, a2d, h2b, al2s, al2d);
    k_agg2 <<<NN / 4, 256, 0, stream>>>(row, adj, al2s, al2d, (const unsigned*)h2b, b2, out);
}